// Round 1
// baseline (541.428 us; speedup 1.0000x reference)
//
#include <hip/hip_runtime.h>
#include <hip/hip_bf16.h>

namespace {

constexpr int kS  = 4096;   // sequence length
constexpr int kD  = 64;     // head dim
constexpr int kQB = 128;    // q-rows per block (4 waves x 32)
constexpr int kKV = 64;     // kv-rows per iteration

typedef __attribute__((ext_vector_type(8))) short bf16x8;
typedef __attribute__((ext_vector_type(4))) short s16x4;
typedef __attribute__((ext_vector_type(4))) float f32x4;

__device__ __forceinline__ unsigned short f2bf(float f) {
  union { __hip_bfloat16 h; unsigned short u; } c;
  c.h = __float2bfloat16(f);
  return c.u;
}

// V^T LDS swizzle: element index for V^T[d][k].
// XOR puts d's low bits (for conflict-free reads: lanes vary d, fixed k)
// and d's high bits (for conflict-free transpose-writes) into k's bank bits.
// Only touches k bits >=2 so 4-element (b64) blocks stay contiguous/aligned.
__device__ __forceinline__ int vt_idx(int d, int k) {
  const int swz = (((d >> 4) & 3) << 4) ^ ((d & 15) << 2);
  return d * kKV + (k ^ swz);
}

__global__ __launch_bounds__(256)
void attn_fwd(const float* __restrict__ Qg, const float* __restrict__ Kg,
              const float* __restrict__ Vg, float* __restrict__ Og) {
  // K tile: row-major bf16 [64][64], 128B rows, 16B-slot XOR swizzle (G4).
  __shared__ __align__(16) unsigned short Klds[kKV * kD];   // 8 KB
  // V^T tile: [d=64][k=64] bf16, swizzled per vt_idx.
  __shared__ __align__(16) unsigned short Vt[kD * kKV];     // 8 KB

  const int tid  = threadIdx.x;
  const int lane = tid & 63;
  const int w    = tid >> 6;
  const int g    = lane >> 4;   // 4-lane-group id (0..3)
  const int lq   = lane & 15;   // q-column / row id within 16

  const size_t base = (size_t)blockIdx.y * kS * kD;
  const int qb = blockIdx.x * kQB + w * 32;

  constexpr float SCL = 0.18033688011112042f;  // (1/sqrt(64)) * log2(e)

  // ---- Q fragments (B-operand of swapped QK^T) ----
  // lane holds Q[qb + st*16 + lq][32*dh + 8*g + i], pre-scaled.
  bf16x8 qf[2][2];
#pragma unroll
  for (int st = 0; st < 2; ++st) {
    const float* qp = Qg + base + (size_t)(qb + st * 16 + lq) * kD + 8 * g;
#pragma unroll
    for (int dh = 0; dh < 2; ++dh) {
      const float4 a = *(const float4*)(qp + dh * 32);
      const float4 b = *(const float4*)(qp + dh * 32 + 4);
      bf16x8 f;
      f[0] = (short)f2bf(a.x * SCL); f[1] = (short)f2bf(a.y * SCL);
      f[2] = (short)f2bf(a.z * SCL); f[3] = (short)f2bf(a.w * SCL);
      f[4] = (short)f2bf(b.x * SCL); f[5] = (short)f2bf(b.y * SCL);
      f[6] = (short)f2bf(b.z * SCL); f[7] = (short)f2bf(b.w * SCL);
      qf[st][dh] = f;
    }
  }

  f32x4 oacc[2][4];  // [q-subtile][d-tile], O^T accumulators
#pragma unroll
  for (int st = 0; st < 2; ++st)
#pragma unroll
    for (int dt = 0; dt < 4; ++dt) oacc[st][dt] = f32x4{0.f, 0.f, 0.f, 0.f};
  float m_run[2] = {-__builtin_inff(), -__builtin_inff()};
  float l_run[2] = {0.0f, 0.0f};

  const int r  = tid >> 2;          // staging row 0..63
  const int c0 = (tid & 3) * 16;    // staging d-offset 0/16/32/48

  for (int kv = 0; kv < kS; kv += kKV) {
    __syncthreads();  // previous iteration's LDS reads complete
    // ---- stage K (swizzled row-major) and V^T (swizzled transpose) ----
    {
      const float* kp = Kg + base + (size_t)(kv + r) * kD + c0;
      const float* vp = Vg + base + (size_t)(kv + r) * kD + c0;
      float4 kq[4], vq[4];
#pragma unroll
      for (int j = 0; j < 4; ++j) kq[j] = *(const float4*)(kp + 4 * j);
#pragma unroll
      for (int j = 0; j < 4; ++j) vq[j] = *(const float4*)(vp + 4 * j);
      const float* kfp = (const float*)kq;
      const float* vfp = (const float*)vq;
      union { unsigned short us[8]; uint4 q; } p0, p1;
#pragma unroll
      for (int j = 0; j < 8; ++j) {
        p0.us[j] = f2bf(kfp[j]);
        p1.us[j] = f2bf(kfp[8 + j]);
      }
      char* kb = (char*)Klds + r * 128;
      const int sw = (r & 7) << 4;
      *(uint4*)(kb + ((c0 * 2) ^ sw))      = p0.q;
      *(uint4*)(kb + ((c0 * 2 + 16) ^ sw)) = p1.q;
#pragma unroll
      for (int j = 0; j < 16; ++j) Vt[vt_idx(c0 + j, r)] = f2bf(vfp[j]);
    }
    __syncthreads();

    // ---- QK^T: S^T tiles (A = K rows, B = Q^T) ----
    f32x4 s[2][4];  // [q-subtile][k-tile of 16]
#pragma unroll
    for (int kt = 0; kt < 4; ++kt) {
      const int krow = kt * 16 + lq;
      const char* kb = (const char*)Klds + krow * 128;
      const int sw = (krow & 7) << 4;
      const bf16x8 kf0 = *(const bf16x8*)(kb + ((16 * g) ^ sw));
      const bf16x8 kf1 = *(const bf16x8*)(kb + ((16 * g + 64) ^ sw));
#pragma unroll
      for (int st = 0; st < 2; ++st) {
        f32x4 acc = __builtin_amdgcn_mfma_f32_16x16x32_bf16(
            kf0, qf[st][0], f32x4{0.f, 0.f, 0.f, 0.f}, 0, 0, 0);
        s[st][kt] = __builtin_amdgcn_mfma_f32_16x16x32_bf16(
            kf1, qf[st][1], acc, 0, 0, 0);
      }
    }

    // ---- online softmax (lane owns q-row lq; 4 lane-group replicas) ----
    bf16x8 pf[2][2];  // [st][kc] P fragments, lane-local repack
#pragma unroll
    for (int st = 0; st < 2; ++st) {
      float mx = s[st][0][0];
#pragma unroll
      for (int kt = 0; kt < 4; ++kt)
#pragma unroll
        for (int rr = 0; rr < 4; ++rr) mx = fmaxf(mx, s[st][kt][rr]);
      mx = fmaxf(mx, __shfl_xor(mx, 16));
      mx = fmaxf(mx, __shfl_xor(mx, 32));
      const float mnew  = fmaxf(m_run[st], mx);
      const float alpha = exp2f(m_run[st] - mnew);
      m_run[st] = mnew;
      float ps = 0.0f;
#pragma unroll
      for (int kt = 0; kt < 4; ++kt)
#pragma unroll
        for (int rr = 0; rr < 4; ++rr) {
          const float e = exp2f(s[st][kt][rr] - mnew);
          s[st][kt][rr] = e;
          ps += e;
        }
      ps += __shfl_xor(ps, 16);
      ps += __shfl_xor(ps, 32);
      l_run[st] = l_run[st] * alpha + ps;
#pragma unroll
      for (int dt = 0; dt < 4; ++dt) oacc[st][dt] *= alpha;
      // P fragment slot i of chunk kc maps k = kc*32 + 16*(i>>2) + 4*g + (i&3)
      // -- all lane-local values; V^T A-frag below uses the same mapping.
#pragma unroll
      for (int kc = 0; kc < 2; ++kc) {
        bf16x8 f;
#pragma unroll
        for (int i = 0; i < 4; ++i) {
          f[i]     = (short)f2bf(s[st][2 * kc][i]);
          f[4 + i] = (short)f2bf(s[st][2 * kc + 1][i]);
        }
        pf[st][kc] = f;
      }
    }

    // ---- PV: O^T += V^T * P^T ----
#pragma unroll
    for (int dt = 0; dt < 4; ++dt) {
      const int d = dt * 16 + lq;
#pragma unroll
      for (int kc = 0; kc < 2; ++kc) {
        const s16x4 lo = *(const s16x4*)&Vt[vt_idx(d, kc * 32 + 4 * g)];
        const s16x4 hi = *(const s16x4*)&Vt[vt_idx(d, kc * 32 + 16 + 4 * g)];
        bf16x8 vf;
        vf[0] = lo[0]; vf[1] = lo[1]; vf[2] = lo[2]; vf[3] = lo[3];
        vf[4] = hi[0]; vf[5] = hi[1]; vf[6] = hi[2]; vf[7] = hi[3];
#pragma unroll
        for (int st = 0; st < 2; ++st)
          oacc[st][dt] = __builtin_amdgcn_mfma_f32_16x16x32_bf16(
              vf, pf[st][kc], oacc[st][dt], 0, 0, 0);
      }
    }
  }

  // ---- epilogue: lane already holds O rows; normalize and store ----
#pragma unroll
  for (int st = 0; st < 2; ++st) {
    const float inv = 1.0f / l_run[st];
    float* op = Og + base + (size_t)(qb + st * 16 + lq) * kD;
#pragma unroll
    for (int dt = 0; dt < 4; ++dt) {
      f32x4 o = oacc[st][dt];
      o *= inv;
      *(f32x4*)(op + dt * 16 + 4 * g) = o;
    }
  }
}

}  // namespace

extern "C" void kernel_launch(void* const* d_in, const int* in_sizes, int n_in,
                              void* d_out, int out_size, void* d_ws, size_t ws_size,
                              hipStream_t stream) {
  const float* Q = (const float*)d_in[0];
  const float* K = (const float*)d_in[1];
  const float* V = (const float*)d_in[2];
  float* O = (float*)d_out;
  dim3 grid(kS / kQB, 2 * 16);  // (q-blocks, B*H)
  attn_fwd<<<grid, 256, 0, stream>>>(Q, K, V, O);
}

// Round 2
// 306.894 us; speedup vs baseline: 1.7642x; 1.7642x over previous
//
#include <hip/hip_runtime.h>
#include <hip/hip_bf16.h>

namespace {

constexpr int kS  = 4096;   // sequence length
constexpr int kD  = 64;     // head dim
constexpr int kQB = 128;    // q-rows per block (4 waves x 32)
constexpr int kKV = 64;     // kv-rows per iteration
constexpr int kBH = 2 * 16; // B*H

typedef __attribute__((ext_vector_type(8))) short bf16x8;
typedef __attribute__((ext_vector_type(4))) short s16x4;
typedef __attribute__((ext_vector_type(4))) float f32x4;
typedef unsigned short u16;

constexpr float SCL = 0.18033688011112042f;  // (1/sqrt(64)) * log2(e)

__device__ __forceinline__ u16 f2bf(float f) {
  union { __hip_bfloat16 h; u16 u; } c;
  c.h = __float2bfloat16(f);
  return c.u;
}

__device__ __forceinline__ void gload_lds16(const void* g, void* l) {
  __builtin_amdgcn_global_load_lds(
      (const __attribute__((address_space(1))) unsigned int*)g,
      (__attribute__((address_space(3))) unsigned int*)l, 16, 0, 0);
}

// V^T LDS swizzle: element index for V^T[d][k]. Touches only k bits >=2 so
// 4-element (b64) chunks stay contiguous/aligned.
__device__ __forceinline__ int vt_idx(int d, int k) {
  const int swz = (((d >> 4) & 3) << 4) ^ ((d & 15) << 2);
  return d * kKV + (k ^ swz);
}

// ---------------- pre-pass: f32 -> bf16 (optionally scaled) ----------------
__global__ __launch_bounds__(256)
void cvt_bf16(const float* __restrict__ src, u16* __restrict__ dst,
              int n8, float scl) {
  const int i = blockIdx.x * 256 + threadIdx.x;
  if (i >= n8) return;
  const float4 a = *(const float4*)(src + (size_t)i * 8);
  const float4 b = *(const float4*)(src + (size_t)i * 8 + 4);
  union { u16 us[8]; uint4 q; } p;
  p.us[0] = f2bf(a.x * scl); p.us[1] = f2bf(a.y * scl);
  p.us[2] = f2bf(a.z * scl); p.us[3] = f2bf(a.w * scl);
  p.us[4] = f2bf(b.x * scl); p.us[5] = f2bf(b.y * scl);
  p.us[6] = f2bf(b.z * scl); p.us[7] = f2bf(b.w * scl);
  *(uint4*)(dst + (size_t)i * 8) = p.q;
}

// ---------------- main kernel (bf16 inputs from ws) ----------------
__global__ __launch_bounds__(256)
void attn_fwd_bf16(const u16* __restrict__ Qb, const u16* __restrict__ Kb,
                   const u16* __restrict__ Vb, float* __restrict__ Og) {
  // K: row-major bf16 [64][64], 128B rows, 16B-slot XOR swizzle; dbuf.
  __shared__ __align__(16) u16 Klds[2][kKV * kD];   // 2 x 8 KB
  // V^T: [d][k] bf16, swizzled per vt_idx; dbuf.
  __shared__ __align__(16) u16 Vt[2][kD * kKV];     // 2 x 8 KB

  const int tid  = threadIdx.x;
  const int lane = tid & 63;
  const int w    = tid >> 6;
  const int g    = lane >> 4;
  const int lq   = lane & 15;

  const size_t base = (size_t)blockIdx.y * kS * kD;
  const int qb = blockIdx.x * kQB + w * 32;

  // ---- Q fragments (pre-scaled bf16): lane holds Q[qrow][dh*32 + 8g + i] ----
  bf16x8 qf[2][2];
#pragma unroll
  for (int st = 0; st < 2; ++st) {
    const u16* qp = Qb + base + (size_t)(qb + st * 16 + lq) * kD + 8 * g;
    qf[st][0] = *(const bf16x8*)(qp);
    qf[st][1] = *(const bf16x8*)(qp + 32);
  }

  f32x4 oacc[2][4];
#pragma unroll
  for (int st = 0; st < 2; ++st)
#pragma unroll
    for (int dt = 0; dt < 4; ++dt) oacc[st][dt] = f32x4{0.f, 0.f, 0.f, 0.f};
  float m_run[2] = {-__builtin_inff(), -__builtin_inff()};
  float l_run[2] = {0.0f, 0.0f};

  const u16* Kh = Kb + base;
  const u16* Vh = Vb + base;

  // V transpose ownership: thread handles 4x4 block (k0..k0+3, d0..d0+3)
  const int k0 = (tid & 15) * 4;
  const int d0 = (tid >> 4) * 4;

  ushort4 vr[4];

  // stage K tile at element offset `off` into Kbuf (pre-swizzled source)
  auto stageK = [&](const u16* Ktile, u16* Kbuf) {
#pragma unroll
    for (int p = 0; p < 2; ++p) {
      const int L = w * 2048 + p * 1024 + lane * 16;  // byte offset in tile
      const int row = L >> 7;
      const int colb = (L & 127) ^ ((row & 7) << 4);
      gload_lds16(Ktile + row * kD + (colb >> 1), Kbuf + (w * 1024 + p * 512));
    }
  };
  auto loadV = [&](const u16* Vtile) {
#pragma unroll
    for (int i = 0; i < 4; ++i)
      vr[i] = *(const ushort4*)(Vtile + (k0 + i) * kD + d0);
  };
  auto writeVt = [&](u16* Vbuf) {
#pragma unroll
    for (int j = 0; j < 4; ++j) {
      s16x4 col;
      col[0] = (short)vr[0][j]; col[1] = (short)vr[1][j];
      col[2] = (short)vr[2][j]; col[3] = (short)vr[3][j];
      *(s16x4*)&Vbuf[vt_idx(d0 + j, k0)] = col;
    }
  };

  // ---- prologue: stage tile 0 ----
  stageK(Kh, Klds[0]);
  loadV(Vh);
  writeVt(Vt[0]);
  __syncthreads();

  int cur = 0;
  for (int t = 0; t < kS / kKV; ++t) {
    const bool pf = (t + 1 < kS / kKV);
    if (pf) {
      stageK(Kh + (size_t)(t + 1) * kKV * kD, Klds[cur ^ 1]);
      loadV(Vh + (size_t)(t + 1) * kKV * kD);
    }

    // ---- QK^T: S^T tiles (A = K rows, B = Q^T) ----
    f32x4 s[2][4];
    __builtin_amdgcn_s_setprio(1);
#pragma unroll
    for (int kt = 0; kt < 4; ++kt) {
      const int krow = kt * 16 + lq;
      const char* kbp = (const char*)Klds[cur] + krow * 128;
      const int sw = (krow & 7) << 4;
      const bf16x8 kf0 = *(const bf16x8*)(kbp + ((16 * g) ^ sw));
      const bf16x8 kf1 = *(const bf16x8*)(kbp + ((16 * g + 64) ^ sw));
#pragma unroll
      for (int st = 0; st < 2; ++st) {
        f32x4 acc = __builtin_amdgcn_mfma_f32_16x16x32_bf16(
            kf0, qf[st][0], f32x4{0.f, 0.f, 0.f, 0.f}, 0, 0, 0);
        s[st][kt] = __builtin_amdgcn_mfma_f32_16x16x32_bf16(
            kf1, qf[st][1], acc, 0, 0, 0);
      }
    }
    __builtin_amdgcn_s_setprio(0);

    // ---- online softmax with defer-max (T13) ----
    bf16x8 pfr[2][2];
#pragma unroll
    for (int st = 0; st < 2; ++st) {
      float mx = s[st][0][0];
#pragma unroll
      for (int kt = 0; kt < 4; ++kt)
#pragma unroll
        for (int rr = 0; rr < 4; ++rr) mx = fmaxf(mx, s[st][kt][rr]);
      mx = fmaxf(mx, __shfl_xor(mx, 16));
      mx = fmaxf(mx, __shfl_xor(mx, 32));
      if (!__all(mx - m_run[st] <= 8.0f)) {
        const float mnew  = fmaxf(m_run[st], mx);
        const float alpha = exp2f(m_run[st] - mnew);
        m_run[st] = mnew;
        l_run[st] *= alpha;
#pragma unroll
        for (int dt = 0; dt < 4; ++dt) oacc[st][dt] *= alpha;
      }
      float ps = 0.0f;
#pragma unroll
      for (int kt = 0; kt < 4; ++kt)
#pragma unroll
        for (int rr = 0; rr < 4; ++rr) {
          const float e = exp2f(s[st][kt][rr] - m_run[st]);
          s[st][kt][rr] = e;
          ps += e;
        }
      ps += __shfl_xor(ps, 16);
      ps += __shfl_xor(ps, 32);
      l_run[st] += ps;
      // P slot i of chunk kc maps k = kc*32 + 16*(i>>2) + 4*g + (i&3)
#pragma unroll
      for (int kc = 0; kc < 2; ++kc) {
        bf16x8 f;
#pragma unroll
        for (int i = 0; i < 4; ++i) {
          f[i]     = (short)f2bf(s[st][2 * kc][i]);
          f[4 + i] = (short)f2bf(s[st][2 * kc + 1][i]);
        }
        pfr[st][kc] = f;
      }
    }

    // ---- PV: O^T += V^T * P^T ----
    __builtin_amdgcn_s_setprio(1);
#pragma unroll
    for (int dt = 0; dt < 4; ++dt) {
      const int d = dt * 16 + lq;
#pragma unroll
      for (int kc = 0; kc < 2; ++kc) {
        const s16x4 lo = *(const s16x4*)&Vt[cur][vt_idx(d, kc * 32 + 4 * g)];
        const s16x4 hi = *(const s16x4*)&Vt[cur][vt_idx(d, kc * 32 + 16 + 4 * g)];
        bf16x8 vf;
        vf[0] = lo[0]; vf[1] = lo[1]; vf[2] = lo[2]; vf[3] = lo[3];
        vf[4] = hi[0]; vf[5] = hi[1]; vf[6] = hi[2]; vf[7] = hi[3];
#pragma unroll
        for (int st = 0; st < 2; ++st)
          oacc[st][dt] = __builtin_amdgcn_mfma_f32_16x16x32_bf16(
              vf, pfr[st][kc], oacc[st][dt], 0, 0, 0);
      }
    }
    __builtin_amdgcn_s_setprio(0);

    if (pf) writeVt(Vt[cur ^ 1]);  // compiler waits vmcnt on vr use
    __syncthreads();               // drains gload_lds; publishes Vt writes
    cur ^= 1;
  }

  // ---- epilogue ----
#pragma unroll
  for (int st = 0; st < 2; ++st) {
    const float inv = 1.0f / l_run[st];
    float* op = Og + base + (size_t)(qb + st * 16 + lq) * kD;
#pragma unroll
    for (int dt = 0; dt < 4; ++dt) {
      f32x4 o = oacc[st][dt];
      o *= inv;
      *(f32x4*)(op + dt * 16 + 4 * g) = o;
    }
  }
}

// ---------------- fallback (round-1 f32 kernel, used if ws too small) -------
__global__ __launch_bounds__(256)
void attn_fwd_f32(const float* __restrict__ Qg, const float* __restrict__ Kg,
                  const float* __restrict__ Vg, float* __restrict__ Og) {
  __shared__ __align__(16) u16 Klds[kKV * kD];
  __shared__ __align__(16) u16 Vts[kD * kKV];

  const int tid  = threadIdx.x;
  const int lane = tid & 63;
  const int w    = tid >> 6;
  const int g    = lane >> 4;
  const int lq   = lane & 15;

  const size_t base = (size_t)blockIdx.y * kS * kD;
  const int qb = blockIdx.x * kQB + w * 32;

  bf16x8 qf[2][2];
#pragma unroll
  for (int st = 0; st < 2; ++st) {
    const float* qp = Qg + base + (size_t)(qb + st * 16 + lq) * kD + 8 * g;
#pragma unroll
    for (int dh = 0; dh < 2; ++dh) {
      const float4 a = *(const float4*)(qp + dh * 32);
      const float4 b = *(const float4*)(qp + dh * 32 + 4);
      bf16x8 f;
      f[0] = (short)f2bf(a.x * SCL); f[1] = (short)f2bf(a.y * SCL);
      f[2] = (short)f2bf(a.z * SCL); f[3] = (short)f2bf(a.w * SCL);
      f[4] = (short)f2bf(b.x * SCL); f[5] = (short)f2bf(b.y * SCL);
      f[6] = (short)f2bf(b.z * SCL); f[7] = (short)f2bf(b.w * SCL);
      qf[st][dh] = f;
    }
  }

  f32x4 oacc[2][4];
#pragma unroll
  for (int st = 0; st < 2; ++st)
#pragma unroll
    for (int dt = 0; dt < 4; ++dt) oacc[st][dt] = f32x4{0.f, 0.f, 0.f, 0.f};
  float m_run[2] = {-__builtin_inff(), -__builtin_inff()};
  float l_run[2] = {0.0f, 0.0f};

  const int r  = tid >> 2;
  const int c0 = (tid & 3) * 16;

  for (int kv = 0; kv < kS; kv += kKV) {
    __syncthreads();
    {
      const float* kp = Kg + base + (size_t)(kv + r) * kD + c0;
      const float* vp = Vg + base + (size_t)(kv + r) * kD + c0;
      float4 kq[4], vq[4];
#pragma unroll
      for (int j = 0; j < 4; ++j) kq[j] = *(const float4*)(kp + 4 * j);
#pragma unroll
      for (int j = 0; j < 4; ++j) vq[j] = *(const float4*)(vp + 4 * j);
      const float* kfp = (const float*)kq;
      const float* vfp = (const float*)vq;
      union { u16 us[8]; uint4 q; } p0, p1;
#pragma unroll
      for (int j = 0; j < 8; ++j) {
        p0.us[j] = f2bf(kfp[j]);
        p1.us[j] = f2bf(kfp[8 + j]);
      }
      char* kb = (char*)Klds + r * 128;
      const int sw = (r & 7) << 4;
      *(uint4*)(kb + ((c0 * 2) ^ sw))      = p0.q;
      *(uint4*)(kb + ((c0 * 2 + 16) ^ sw)) = p1.q;
#pragma unroll
      for (int j = 0; j < 16; ++j) Vts[vt_idx(c0 + j, r)] = f2bf(vfp[j]);
    }
    __syncthreads();

    f32x4 s[2][4];
#pragma unroll
    for (int kt = 0; kt < 4; ++kt) {
      const int krow = kt * 16 + lq;
      const char* kb = (const char*)Klds + krow * 128;
      const int sw = (krow & 7) << 4;
      const bf16x8 kf0 = *(const bf16x8*)(kb + ((16 * g) ^ sw));
      const bf16x8 kf1 = *(const bf16x8*)(kb + ((16 * g + 64) ^ sw));
#pragma unroll
      for (int st = 0; st < 2; ++st) {
        f32x4 acc = __builtin_amdgcn_mfma_f32_16x16x32_bf16(
            kf0, qf[st][0], f32x4{0.f, 0.f, 0.f, 0.f}, 0, 0, 0);
        s[st][kt] = __builtin_amdgcn_mfma_f32_16x16x32_bf16(
            kf1, qf[st][1], acc, 0, 0, 0);
      }
    }

    bf16x8 pfr[2][2];
#pragma unroll
    for (int st = 0; st < 2; ++st) {
      float mx = s[st][0][0];
#pragma unroll
      for (int kt = 0; kt < 4; ++kt)
#pragma unroll
        for (int rr = 0; rr < 4; ++rr) mx = fmaxf(mx, s[st][kt][rr]);
      mx = fmaxf(mx, __shfl_xor(mx, 16));
      mx = fmaxf(mx, __shfl_xor(mx, 32));
      const float mnew  = fmaxf(m_run[st], mx);
      const float alpha = exp2f(m_run[st] - mnew);
      m_run[st] = mnew;
      float ps = 0.0f;
#pragma unroll
      for (int kt = 0; kt < 4; ++kt)
#pragma unroll
        for (int rr = 0; rr < 4; ++rr) {
          const float e = exp2f(s[st][kt][rr] - mnew);
          s[st][kt][rr] = e;
          ps += e;
        }
      ps += __shfl_xor(ps, 16);
      ps += __shfl_xor(ps, 32);
      l_run[st] = l_run[st] * alpha + ps;
#pragma unroll
      for (int dt = 0; dt < 4; ++dt) oacc[st][dt] *= alpha;
#pragma unroll
      for (int kc = 0; kc < 2; ++kc) {
        bf16x8 f;
#pragma unroll
        for (int i = 0; i < 4; ++i) {
          f[i]     = (short)f2bf(s[st][2 * kc][i]);
          f[4 + i] = (short)f2bf(s[st][2 * kc + 1][i]);
        }
        pfr[st][kc] = f;
      }
    }

#pragma unroll
    for (int dt = 0; dt < 4; ++dt) {
      const int d = dt * 16 + lq;
#pragma unroll
      for (int kc = 0; kc < 2; ++kc) {
        const s16x4 lo = *(const s16x4*)&Vts[vt_idx(d, kc * 32 + 4 * g)];
        const s16x4 hi = *(const s16x4*)&Vts[vt_idx(d, kc * 32 + 16 + 4 * g)];
        bf16x8 vf;
        vf[0] = lo[0]; vf[1] = lo[1]; vf[2] = lo[2]; vf[3] = lo[3];
        vf[4] = hi[0]; vf[5] = hi[1]; vf[6] = hi[2]; vf[7] = hi[3];
#pragma unroll
        for (int st = 0; st < 2; ++st)
          oacc[st][dt] = __builtin_amdgcn_mfma_f32_16x16x32_bf16(
              vf, pfr[st][kc], oacc[st][dt], 0, 0, 0);
      }
    }
  }

#pragma unroll
  for (int st = 0; st < 2; ++st) {
    const float inv = 1.0f / l_run[st];
    float* op = Og + base + (size_t)(qb + st * 16 + lq) * kD;
#pragma unroll
    for (int dt = 0; dt < 4; ++dt) {
      f32x4 o = oacc[st][dt];
      o *= inv;
      *(f32x4*)(op + dt * 16 + 4 * g) = o;
    }
  }
}

}  // namespace

extern "C" void kernel_launch(void* const* d_in, const int* in_sizes, int n_in,
                              void* d_out, int out_size, void* d_ws, size_t ws_size,
                              hipStream_t stream) {
  const float* Q = (const float*)d_in[0];
  const float* K = (const float*)d_in[1];
  const float* V = (const float*)d_in[2];
  float* O = (float*)d_out;
  const int n = in_sizes[0];                 // B*H*S*D elements per tensor
  const size_t tbytes = (size_t)n * 2;       // bf16 bytes per tensor
  dim3 grid(kS / kQB, kBH);

  if (ws_size >= 3 * tbytes) {
    u16* Qb = (u16*)d_ws;
    u16* Kb = Qb + n;
    u16* Vb = Kb + n;
    const int n8 = n / 8;
    const int cblk = (n8 + 255) / 256;
    cvt_bf16<<<cblk, 256, 0, stream>>>(Q, Qb, n8, SCL);
    cvt_bf16<<<cblk, 256, 0, stream>>>(K, Kb, n8, 1.0f);
    cvt_bf16<<<cblk, 256, 0, stream>>>(V, Vb, n8, 1.0f);
    attn_fwd_bf16<<<grid, 256, 0, stream>>>(Qb, Kb, Vb, O);
  } else {
    attn_fwd_f32<<<grid, 256, 0, stream>>>(Q, K, V, O);
  }
}